// Round 2
// baseline (224.165 us; speedup 1.0000x reference)
//
#include <hip/hip_runtime.h>
#include <math.h>

#define NB 8
#define NN 150
#define NE 299          // 2*N-1
#define NNODE (NB*NN)   // 1200

// workspace strides
#define EW_STRIDE 2400  // per-layer EWq table (299 rows x 8)
#define SE_STRIDE 4800  // per-layer SE table (150 x 32)
#define W2_STRIDE 64    // per-layer W2 table (9x6 padded)

struct Quat { float w, x, y, z; };

__device__ inline Quat qmul(Quat a, Quat b) {
    Quat r;
    r.w = a.w*b.w - a.x*b.x - a.y*b.y - a.z*b.z;
    r.x = a.w*b.x + a.x*b.w + a.y*b.z - a.z*b.y;
    r.y = a.w*b.y - a.x*b.z + a.y*b.w + a.z*b.x;
    r.z = a.w*b.z + a.x*b.y - a.y*b.x + a.z*b.w;
    return r;
}
__device__ inline Quat qconj(Quat a) { return Quat{a.w, -a.x, -a.y, -a.z}; }

__device__ inline float3 qrot(Quat q, float3 v) {
    float tx = 2.f*(q.y*v.z - q.z*v.y);
    float ty = 2.f*(q.z*v.x - q.x*v.z);
    float tz = 2.f*(q.x*v.y - q.y*v.x);
    float cx = q.y*tz - q.z*ty;
    float cy = q.z*tx - q.x*tz;
    float cz = q.x*ty - q.y*tx;
    return float3{v.x + q.w*tx + cx, v.y + q.w*ty + cy, v.z + q.w*tz + cz};
}

// ---------------------------------------------------------------------------
// Prep: blocks [0,1200) do per-node layer-1 quantities (h, A, C, dC, SC1,
// padded q/x). Blocks [1200,1256) build per-layer tables:
//   W2 = WmG@Wq (9x6), EWq = WmE@Wq (299x6), SE_i = sum_{j!=i} WmE[149+i-j].
// ---------------------------------------------------------------------------
struct PrepArgs {
    const float *quats, *trans, *feats; const int* tp;
    const float *wm1, *bm1, *wq1, *bq1;
    const float* wmE[4]; const float* wmG[4]; const float* wqL[4];
    float *h, *A, *C, *dC, *qA, *xA, *SC, *EWq, *W2, *SE;
};

__global__ __launch_bounds__(192) void prep_kernel(PrepArgs p) {
    const int tid = threadIdx.x;
    const int bid = blockIdx.x;
    if (bid < NNODE) {
        __shared__ float sh[30];
        __shared__ float sC[32];
        const int n = bid, b = n / NN;
        if (tid < 30) {
            float v;
            if      (tid < 4)  v = p.quats[n*4 + tid];
            else if (tid < 7)  v = p.trans[n*3 + (tid-4)];
            else if (tid < 29) v = p.feats[n*22 + (tid-7)];
            else               v = (float)p.tp[0] * 1e-3f;   // t / T_STEPS
            sh[tid] = v;
            p.h[n*64 + tid] = v;
        }
        if (tid < 4) {
            p.qA[n*4 + tid] = p.quats[n*4 + tid];
            p.xA[n*4 + tid] = (tid < 3) ? p.trans[n*3 + tid] : 0.f;
        }
        __syncthreads();
        if (tid < 32) {
            float a = p.bm1[tid];
#pragma unroll
            for (int d = 0; d < 30; ++d) a = fmaf(sh[d], p.wm1[d*32 + tid], a);
            p.A[n*32 + tid] = a;
        } else if (tid >= 64 && tid < 96) {
            const int k = tid - 64;
            float c = 0.f;
#pragma unroll
            for (int d = 0; d < 30; ++d) c = fmaf(sh[d], p.wm1[(30+d)*32 + k], c);
            sC[k] = c;
            p.C[n*32 + k] = c;
        }
        __syncthreads();
        if (tid < 6) {
            float acc = p.bq1[tid];
#pragma unroll
            for (int k = 0; k < 32; ++k) acc = fmaf(sC[k], p.wq1[k*6 + tid], acc);
            p.dC[n*8 + tid] = acc;
        } else if (tid >= 32 && tid < 64) {
            atomicAdd(&p.SC[b*32 + (tid-32)], sC[tid-32]);
        }
    } else {
        const int t = bid - NNODE;
        const int L = t / 14, r = t - L*14;
        const float* wmE = p.wmE[L];
        const float* wmG = p.wmG[L];
        const float* wq  = p.wqL[L];
        if (r == 0) {                       // W2 = WmG @ Wq  (9x6)
            if (tid < 54) {
                const int tt = tid / 6, d = tid - tt*6;
                float acc = 0.f;
#pragma unroll
                for (int k = 0; k < 32; ++k) acc = fmaf(wmG[tt*32+k], wq[k*6+d], acc);
                p.W2[L*W2_STRIDE + tid] = acc;
            }
        } else if (r <= 3) {                // EWq = WmE @ Wq (299x6)
            const int base = (r-1) * 100;
            for (int idx = tid; idx < 600; idx += 192) {
                const int rl = idx / 6, d = idx - rl*6;
                const int row = base + rl;
                if (row < NE) {
                    float acc = 0.f;
#pragma unroll
                    for (int k = 0; k < 32; ++k) acc = fmaf(wmE[row*32+k], wq[k*6+d], acc);
                    p.EWq[L*EW_STRIDE + row*8 + d] = acc;
                }
            }
        } else {                            // SE_i[k] = sum rows i..i+149 minus row 149
            const int base = (r-4) * 15;
            for (int idx = tid; idx < 15*32; idx += 192) {
                const int il = idx >> 5, k = idx & 31;
                const int i = base + il;
                float acc = -wmE[149*32 + k];
                for (int rr = i; rr < i + 150; ++rr) acc += wmE[rr*32 + k];
                p.SE[L*SE_STRIDE + i*32 + k] = acc;
            }
        }
    }
}

// ---------------------------------------------------------------------------
// Pair kernel: block = (b,i), 192 threads, thread j = neighbor.
// Per-pair work: geometry g[9], gW2[6], delta assembly, x/s terms.
// Reduce 16 values. Epilogue: msum (decomposed), o, relu, next-layer A/C/dC.
// ---------------------------------------------------------------------------
struct PairArgs {
    const float *qin, *xin, *dCin;
    float *h, *A, *C;                          // in-place (own-block only)
    const float *wmG, *wq, *EWq, *W2, *SE, *SC;
    const float *wf, *bf;
    const float *wmn, *bmn, *wqn, *bqn;        // next layer
    float *dCout, *SCnext, *qout, *xout, *dout;
};

template<int HD, bool LAST>
__global__ __launch_bounds__(192) void pair_kernel(PairArgs p) {
    __shared__ float sW2[54];
    __shared__ float sdA[8];
    __shared__ float sAi[32], sCi[32], sSE[32], sSC[32];
    __shared__ float sHi[64];
    __shared__ float sQX[8];
    __shared__ float sRed[3][16];
    __shared__ float sTot[16];
    __shared__ float sMsum[32];
    __shared__ float sO[64];
    __shared__ float sCn[32];

    const int tid = threadIdx.x;
    const int nodeI = blockIdx.x;
    const int b = nodeI / NN, i = nodeI - b*NN;

    if (tid < 54) sW2[tid] = p.W2[tid];
    if (tid >= 64  && tid < 96)  sAi[tid-64]  = p.A[nodeI*32 + tid-64];
    if (tid >= 96  && tid < 128) sCi[tid-96]  = p.C[nodeI*32 + tid-96];
    if (tid >= 128 && tid < 160) sSE[tid-128] = p.SE[i*32 + tid-128];
    if (tid >= 160)              sSC[tid-160] = p.SC[b*32 + tid-160];
    if (!LAST && tid < HD)       sHi[tid]     = p.h[nodeI*64 + tid];
    if (tid < 4)                 sQX[tid]     = p.qin[nodeI*4 + tid];
    if (tid >= 4 && tid < 8)     sQX[tid]     = p.xin[nodeI*4 + tid-4];
    __syncthreads();
    if (tid < 6) {
        float acc = 0.f;
#pragma unroll
        for (int k = 0; k < 32; ++k) acc = fmaf(sAi[k], p.wq[k*6 + tid], acc);
        sdA[tid] = acc;
    }
    __syncthreads();

    float vals[16];
#pragma unroll
    for (int v = 0; v < 16; ++v) vals[v] = 0.f;

    const int j = tid;
    if (j < NN) {
        const int nodeJ = b*NN + j;
        const float4 qj4 = *(const float4*)(p.qin + nodeJ*4);
        const float4 xj4 = *(const float4*)(p.xin + nodeJ*4);
        Quat  qi = {sQX[0], sQX[1], sQX[2], sQX[3]};
        float3 xi = {sQX[4], sQX[5], sQX[6]};
        Quat  qj = {qj4.x, qj4.y, qj4.z, qj4.w};
        float3 xj = {xj4.x, xj4.y, xj4.z};
        float3 diff = {xi.x - xj.x, xi.y - xj.y, xi.z - xj.z};
        Quat qjc = qconj(qj);
        float3 lx = qrot(qjc, diff);
        Quat lq = qmul(qmul(qjc, qi), qj);
        const float d2 = diff.x*diff.x + diff.y*diff.y + diff.z*diff.z;
        const float dt = fabsf(qi.w*qj.w + qi.x*qj.x + qi.y*qj.y + qi.z*qj.z);
        const float g[9] = {lx.x, lx.y, lx.z, lq.w, lq.x, lq.y, lq.z, d2, dt};
        const float mm = (j == i) ? 0.f : 1.f;

        // delta = mm * (dA + dC_j + EWq[149+i-j] + g@W2)
        const int row = NN - 1 + i - j;
        const float4 e0 = *(const float4*)(p.EWq + row*8);
        const float2 e1 = *(const float2*)(p.EWq + row*8 + 4);
        const float4 c0 = *(const float4*)(p.dCin + nodeJ*8);
        const float2 c1 = *(const float2*)(p.dCin + nodeJ*8 + 4);
        const float ew[6] = {e0.x, e0.y, e0.z, e0.w, e1.x, e1.y};
        const float dc[6] = {c0.x, c0.y, c0.z, c0.w, c1.x, c1.y};
        float dl[6];
#pragma unroll
        for (int d = 0; d < 6; ++d) {
            float acc = sdA[d] + dc[d] + ew[d];
#pragma unroll
            for (int t = 0; t < 9; ++t) acc = fmaf(g[t], sW2[t*6 + d], acc);
            dl[d] = acc * mm;
        }

        // x-term (j == i contributes x_i exactly: lx = 0, dl = 0)
        float3 lxd = {lx.x + dl[3], lx.y + dl[4], lx.z + dl[5]};
        float3 xt = qrot(qj, lxd);
        vals[9]  = xt.x + xj.x;
        vals[10] = xt.y + xj.y;
        vals[11] = xt.z + xj.z;

        // s-term
        Quat vq = {0.f, dl[0], dl[1], dl[2]};
        Quat sp = qmul(lq, vq);
        vals[12] = lq.w + sp.w;
        vals[13] = lq.x + sp.x;
        vals[14] = lq.y + sp.y;
        vals[15] = lq.z + sp.z;

        // masked geometry sums (for msum decomposition)
#pragma unroll
        for (int t = 0; t < 9; ++t) vals[t] = g[t] * mm;
    }

    // reduce 16 values across 192 threads
#pragma unroll
    for (int v = 0; v < 16; ++v) {
        float x = vals[v];
        for (int off = 32; off > 0; off >>= 1)
            x += __shfl_down(x, off, 64);
        vals[v] = x;
    }
    const int wave = tid >> 6;
    const int lane = tid & 63;
    if (lane == 0) {
#pragma unroll
        for (int v = 0; v < 16; ++v) sRed[wave][v] = vals[v];
    }
    __syncthreads();
    if (tid < 16) sTot[tid] = sRed[0][tid] + sRed[1][tid] + sRed[2][tid];
    __syncthreads();

    // q/x update (independent of the msum/o path)
    if (tid == 96) {
        const float inv = 1.0f / (float)(NN - 1);
        const float ux0 = sTot[9]*inv, ux1 = sTot[10]*inv, ux2 = sTot[11]*inv;
        Quat s = {sTot[12], sTot[13], sTot[14], sTot[15]};
        const float nrm = sqrtf(s.w*s.w + s.x*s.x + s.y*s.y + s.z*s.z);
        const float invn = 1.0f / fmaxf(nrm, 1e-12f);
        Quat u = {s.w*invn, s.x*invn, s.y*invn, s.z*invn};
        Quat qi = {sQX[0], sQX[1], sQX[2], sQX[3]};
        Quat uq = qmul(qmul(qi, u), qconj(qi));
        if (LAST) {
            float* o = p.dout + nodeI*7;
            o[0] = uq.w; o[1] = uq.x; o[2] = uq.y; o[3] = uq.z;
            o[4] = ux0;  o[5] = ux1;  o[6] = ux2;
        } else {
            p.qout[nodeI*4+0] = uq.w; p.qout[nodeI*4+1] = uq.x;
            p.qout[nodeI*4+2] = uq.y; p.qout[nodeI*4+3] = uq.z;
            p.xout[nodeI*4+0] = ux0;  p.xout[nodeI*4+1] = ux1;
            p.xout[nodeI*4+2] = ux2;  p.xout[nodeI*4+3] = 0.f;
        }
    }

    if (!LAST) {
        // msum = 149*A_i + (SC - C_i) + SE_i + G @ WmG
        if (tid < 32) {
            float acc = 149.f*sAi[tid] + (sSC[tid] - sCi[tid]) + sSE[tid];
#pragma unroll
            for (int t = 0; t < 9; ++t) acc = fmaf(sTot[t], p.wmG[t*32 + tid], acc);
            sMsum[tid] = acc;
        }
        __syncthreads();
        // o = [h, msum] @ Wf + bf ; h' = relu(o)
        if (tid < 64) {
            float acc = p.bf[tid];
#pragma unroll
            for (int d = 0; d < HD; ++d) acc = fmaf(sHi[d], p.wf[d*64 + tid], acc);
#pragma unroll
            for (int k = 0; k < 32; ++k) acc = fmaf(sMsum[k], p.wf[(HD+k)*64 + tid], acc);
            const float hv = acc > 0.f ? acc : 0.f;
            sO[tid] = hv;
            p.h[nodeI*64 + tid] = hv;
        }
        __syncthreads();
        // next-layer A', C'
        if (tid < 32) {
            float a = p.bmn[tid];
#pragma unroll
            for (int d = 0; d < 64; ++d) a = fmaf(sO[d], p.wmn[d*32 + tid], a);
            p.A[nodeI*32 + tid] = a;
        } else if (tid >= 64 && tid < 96) {
            const int k = tid - 64;
            float c = 0.f;
#pragma unroll
            for (int d = 0; d < 64; ++d) c = fmaf(sO[d], p.wmn[(64+d)*32 + k], c);
            sCn[k] = c;
            p.C[nodeI*32 + k] = c;
        }
        __syncthreads();
        if (tid < 6) {
            float acc = p.bqn[tid];
#pragma unroll
            for (int k = 0; k < 32; ++k) acc = fmaf(sCn[k], p.wqn[k*6 + tid], acc);
            p.dCout[nodeI*8 + tid] = acc;
        } else if (tid >= 32 && tid < 64) {
            atomicAdd(&p.SCnext[b*32 + (tid-32)], sCn[tid-32]);
        }
    }
}

// ---------------------------------------------------------------------------

extern "C" void kernel_launch(void* const* d_in, const int* in_sizes, int n_in,
                              void* d_out, int out_size, void* d_ws, size_t ws_size,
                              hipStream_t stream) {
    const float* quats = (const float*)d_in[0];
    const float* trans = (const float*)d_in[1];
    const float* feats = (const float*)d_in[2];
    const int*   tptr  = (const int*)d_in[4];

    const float* wm[4] = {(const float*)d_in[5],  (const float*)d_in[11],
                          (const float*)d_in[17], (const float*)d_in[23]};
    const float* bm[4] = {(const float*)d_in[6],  (const float*)d_in[12],
                          (const float*)d_in[18], (const float*)d_in[24]};
    const float* wf[4] = {(const float*)d_in[7],  (const float*)d_in[13],
                          (const float*)d_in[19], (const float*)d_in[25]};
    const float* bf[4] = {(const float*)d_in[8],  (const float*)d_in[14],
                          (const float*)d_in[20], (const float*)d_in[26]};
    const float* wq[4] = {(const float*)d_in[9],  (const float*)d_in[15],
                          (const float*)d_in[21], (const float*)d_in[27]};
    const float* bq[4] = {(const float*)d_in[10], (const float*)d_in[16],
                          (const float*)d_in[22], (const float*)d_in[28]};

    const int HDs[4] = {30, 64, 64, 64};
    const float* wmE[4]; const float* wmG[4];
    for (int L = 0; L < 4; ++L) {
        wmE[L] = wm[L] + 2*HDs[L]*32;
        wmG[L] = wm[L] + (2*HDs[L] + NE)*32;
    }

    float* ws  = (float*)d_ws;
    float* h   = ws;                   // 1200*64
    float* A   = h   + NNODE*64;       // 1200*32
    float* C   = A   + NNODE*32;       // 1200*32
    float* dCa = C   + NNODE*32;       // 1200*8
    float* dCb = dCa + NNODE*8;        // 1200*8
    float* qA  = dCb + NNODE*8;        // 1200*4
    float* xA  = qA  + NNODE*4;        // 1200*4
    float* qB  = xA  + NNODE*4;        // 1200*4
    float* xB  = qB  + NNODE*4;        // 1200*4
    float* SC  = xB  + NNODE*4;        // 4*8*32 = 1024 (zeroed)
    float* EWq = SC  + 1024;           // 4*2400
    float* W2  = EWq + 4*EW_STRIDE;    // 4*64
    float* SE  = W2  + 4*W2_STRIDE;    // 4*4800

    hipMemsetAsync(SC, 0, 1024*sizeof(float), stream);

    PrepArgs pp;
    pp.quats = quats; pp.trans = trans; pp.feats = feats; pp.tp = tptr;
    pp.wm1 = wm[0]; pp.bm1 = bm[0]; pp.wq1 = wq[0]; pp.bq1 = bq[0];
    for (int L = 0; L < 4; ++L) { pp.wmE[L] = wmE[L]; pp.wmG[L] = wmG[L]; pp.wqL[L] = wq[L]; }
    pp.h = h; pp.A = A; pp.C = C; pp.dC = dCa; pp.qA = qA; pp.xA = xA;
    pp.SC = SC; pp.EWq = EWq; pp.W2 = W2; pp.SE = SE;
    prep_kernel<<<dim3(NNODE + 56), dim3(192), 0, stream>>>(pp);

    float* dout = (float*)d_out;

    auto mkargs = [&](int L, const float* qin, const float* xin, const float* dCin,
                      float* dCout, float* qout, float* xout, float* dO) {
        PairArgs a;
        a.qin = qin; a.xin = xin; a.dCin = dCin;
        a.h = h; a.A = A; a.C = C;
        a.wmG = wmG[L]; a.wq = wq[L];
        a.EWq = EWq + L*EW_STRIDE; a.W2 = W2 + L*W2_STRIDE;
        a.SE = SE + L*SE_STRIDE; a.SC = SC + L*256;
        a.wf = wf[L]; a.bf = bf[L];
        const int Ln = (L < 3) ? L+1 : L;   // next-layer weights (unused for LAST)
        a.wmn = wm[Ln]; a.bmn = bm[Ln]; a.wqn = wq[Ln]; a.bqn = bq[Ln];
        a.dCout = dCout; a.SCnext = SC + (L < 3 ? (L+1)*256 : L*256);
        a.qout = qout; a.xout = xout; a.dout = dO;
        return a;
    };

    // L1: q/x in A-set, out B-set; dC in a, out b
    pair_kernel<30, false><<<dim3(NNODE), dim3(192), 0, stream>>>(
        mkargs(0, qA, xA, dCa, dCb, qB, xB, nullptr));
    // L2: B -> A
    pair_kernel<64, false><<<dim3(NNODE), dim3(192), 0, stream>>>(
        mkargs(1, qB, xB, dCb, dCa, qA, xA, nullptr));
    // L3: A -> B
    pair_kernel<64, false><<<dim3(NNODE), dim3(192), 0, stream>>>(
        mkargs(2, qA, xA, dCa, dCb, qB, xB, nullptr));
    // L4: B -> d_out
    pair_kernel<64, true ><<<dim3(NNODE), dim3(192), 0, stream>>>(
        mkargs(3, qB, xB, dCb, nullptr, nullptr, nullptr, dout));
}